// Round 14
// baseline (262.865 us; speedup 1.0000x reference)
//
#include <hip/hip_runtime.h>
#include <hip/hip_bf16.h>
#include <stdint.h>

typedef int v4i __attribute__((ext_vector_type(4)));

#define AS_GLOBAL(p) ((const __attribute__((address_space(1))) void*)(p))
#define AS_LDS(p)    ((__attribute__((address_space(3))) void*)(p))

// ---------------- merged prepass: rows [0,M) = x - izp (+rowsum); rows [M, M+N) = w - 128
__global__ __launch_bounds__(256) void prep_kernel(const int* __restrict__ x,
                                                   const int* __restrict__ w,
                                                   const int* __restrict__ izp_p,
                                                   signed char* __restrict__ xs,
                                                   signed char* __restrict__ wsq,
                                                   int* __restrict__ rowsum, int M, int K) {
    int row = blockIdx.x;
    int n4 = K >> 2;
    if (row < M) {
        int izp = izp_p[0];
        const int4* xr = (const int4*)(x + (long)row * K);
        uint32_t* xo = (uint32_t*)(xs + (long)row * K);
        int sum = 0;
        for (int i = threadIdx.x; i < n4; i += 256) {
            int4 v = xr[i];
            int a0 = v.x - izp, a1 = v.y - izp, a2 = v.z - izp, a3 = v.w - izp;
            sum += a0 + a1 + a2 + a3;
            xo[i] = (uint32_t)(a0 & 0xFF) | ((uint32_t)(a1 & 0xFF) << 8) |
                    ((uint32_t)(a2 & 0xFF) << 16) | ((uint32_t)(a3 & 0xFF) << 24);
        }
        sum += __shfl_down(sum, 32);
        sum += __shfl_down(sum, 16);
        sum += __shfl_down(sum, 8);
        sum += __shfl_down(sum, 4);
        sum += __shfl_down(sum, 2);
        sum += __shfl_down(sum, 1);
        __shared__ int red[4];
        if ((threadIdx.x & 63) == 0) red[threadIdx.x >> 6] = sum;
        __syncthreads();
        if (threadIdx.x == 0) rowsum[row] = red[0] + red[1] + red[2] + red[3];
    } else {
        int wrow = row - M;
        const int4* wr = (const int4*)(w + (long)wrow * K);
        uint32_t* wo = (uint32_t*)(wsq + (long)wrow * K);
        for (int i = threadIdx.x; i < n4; i += 256) {
            int4 v = wr[i];
            int a0 = v.x - 128, a1 = v.y - 128, a2 = v.z - 128, a3 = v.w - 128;
            wo[i] = (uint32_t)(a0 & 0xFF) | ((uint32_t)(a1 & 0xFF) << 8) |
                    ((uint32_t)(a2 & 0xFF) << 16) | ((uint32_t)(a3 & 0xFF) << 24);
        }
    }
}

// ---------------- main GEMM: 256x256 tile, BK=64 int8, B DIRECT-TO-REGISTERS ----------------
// R14: break the "first MFMA needs last ds_read" chain that serialized LDS and MFMA
//      in R2-R13 (9 probes, all ~2765 cyc/K-tile = LDS+MFMA sum). B-fragments load
//      straight from global (L2 panel, 2x redundancy) into ping-ponged regs, one
//      tile ahead. LDS is A-only (2 x 16KB dbuf): pipe demand ~900 cyc < MFMA 1306;
//      MFMA mi-major gates only on af[mi] = the wave's mi-th read (arrival order =
//      consumption order -> streaming). A-path swizzle identical to R13 (0 conflicts).
//      Regs: af[8]+bfA[4]+bfB[4]=64 v4i + acc 128 ~ 220 < 256 (R11 lesson).

#define BAR  __builtin_amdgcn_s_barrier()
#define LGKM0 asm volatile("s_waitcnt lgkmcnt(0)" ::: "memory")
#define VM0  asm volatile("s_waitcnt vmcnt(0)" ::: "memory")
#define PRIO1 __builtin_amdgcn_s_setprio(1)
#define PRIO0 __builtin_amdgcn_s_setprio(0)

// stage A K-tile `tile` into buffer bb (16KB): 2 gloads/wave, 1KB each.
#define STAGE_A(bb, tile) do {                                                        \
    long ko_ = (long)(tile) * 64;                                                     \
    signed char* lb_ = lds + (bb) * 16384 + w * 2048;                                 \
    __builtin_amdgcn_global_load_lds(AS_GLOBAL(gA0 + ko_), AS_LDS(lb_),        16, 0, 0); \
    __builtin_amdgcn_global_load_lds(AS_GLOBAL(gA1 + ko_), AS_LDS(lb_ + 1024), 16, 0, 0); \
  } while (0)

#define M1(mi, ni, BC)                                                                 \
    acc[mi][ni] = __builtin_amdgcn_mfma_i32_16x16x64_i8(af[mi], BC[ni], acc[mi][ni], 0, 0, 0);

// mi-major: each af[mi] gates exactly its 4 MFMAs; B is already in registers.
#define MFMA32(BC) do {                                                                \
    M1(0, 0, BC) M1(0, 1, BC) M1(0, 2, BC) M1(0, 3, BC)                                \
    M1(1, 0, BC) M1(1, 1, BC) M1(1, 2, BC) M1(1, 3, BC)                                \
    M1(2, 0, BC) M1(2, 1, BC) M1(2, 2, BC) M1(2, 3, BC)                                \
    M1(3, 0, BC) M1(3, 1, BC) M1(3, 2, BC) M1(3, 3, BC)                                \
    M1(4, 0, BC) M1(4, 1, BC) M1(4, 2, BC) M1(4, 3, BC)                                \
    M1(5, 0, BC) M1(5, 1, BC) M1(5, 2, BC) M1(5, 3, BC)                                \
    M1(6, 0, BC) M1(6, 1, BC) M1(6, 2, BC) M1(6, 3, BC)                                \
    M1(7, 0, BC) M1(7, 1, BC) M1(7, 2, BC) M1(7, 3, BC)                                \
  } while (0)

// One K-tile: consume BC (tile t, already in regs) + af from LDS buf b;
// prefetch BN (tile t+1) and stage A(t+1) into buf b^1.
// Hazards: buf b^1's readers were iter t-1, retired at its LGKM0+BAR. VM0 before
// BAR -> A(t+1) LDS-resident and BN loads landed for next iter.
#define ITER(b, BC, BN, t) do {                                                        \
    int tn_ = (t) + 1; if (tn_ >= NT) tn_ = NT - 1;                                    \
    long bo_ = (long)tn_ * 64;                                                         \
    BN[0] = *(const v4i*)(gBf0 + bo_);                                                 \
    BN[1] = *(const v4i*)(gBf1 + bo_);                                                 \
    BN[2] = *(const v4i*)(gBf2 + bo_);                                                 \
    BN[3] = *(const v4i*)(gBf3 + bo_);                                                 \
    STAGE_A((b) ^ 1, tn_);                                                             \
    af[0] = *(const v4i*)(lds + (b) * 16384 + aoffc + 0 * 1024);                       \
    af[1] = *(const v4i*)(lds + (b) * 16384 + aoffc + 1 * 1024);                       \
    af[2] = *(const v4i*)(lds + (b) * 16384 + aoffc + 2 * 1024);                       \
    af[3] = *(const v4i*)(lds + (b) * 16384 + aoffc + 3 * 1024);                       \
    af[4] = *(const v4i*)(lds + (b) * 16384 + aoffc + 4 * 1024);                       \
    af[5] = *(const v4i*)(lds + (b) * 16384 + aoffc + 5 * 1024);                       \
    af[6] = *(const v4i*)(lds + (b) * 16384 + aoffc + 6 * 1024);                       \
    af[7] = *(const v4i*)(lds + (b) * 16384 + aoffc + 7 * 1024);                       \
    PRIO1; MFMA32(BC); PRIO0;                                                          \
    LGKM0; VM0; BAR;                                                                   \
  } while (0)

__global__ __launch_bounds__(512, 2) void gemm_i8_bd(
    const signed char* __restrict__ A,   // xs [M,K]
    const signed char* __restrict__ B,   // ws [N,K]
    const int* __restrict__ rowsum, const float* __restrict__ wscale,
    const int* __restrict__ wzp, const float* __restrict__ bias,
    const float* __restrict__ iscale, float* __restrict__ C,
    int M, int N, int K) {
  __shared__ signed char lds[32768];   // A only: 2 x 16KB double buffer
  const int tid = threadIdx.x;
  const int w = tid >> 6, l = tid & 63;
  const int wm = w >> 2, wn = w & 3;
  const int fr = l & 15, fq = l >> 4;

  int nwg = gridDim.x, bid = blockIdx.x;
  if ((nwg & 7) == 0) { int cpx = nwg >> 3; bid = (bid & 7) * cpx + (bid >> 3); }
  const int ntiles = N >> 8;
  const int mt = bid / ntiles, nt = bid - mt * ntiles;
  const long brow = (long)mt << 8, bcol = (long)nt << 8;

  const int NT = K >> 6;      // K-tiles of 64 bytes

  // A staging lane constants (R13 scheme, proven 0-conflict):
  // gload g covers rows (w*2+g)*16 + (l>>2); source chunk (l&3)^((l>>3)&3).
  const int sr = l >> 2;
  const int schunk = ((l & 3) ^ ((l >> 3) & 3)) << 4;
  const signed char* gA0 = A + (brow + (w * 2 + 0) * 16 + sr) * (long)K + schunk;
  const signed char* gA1 = A + (brow + (w * 2 + 1) * 16 + sr) * (long)K + schunk;

  // A fragment read offsets: row*64 + (fq ^ ((fr>>1)&3))*16; mi step 1024.
  const int rdc = (fq ^ ((fr >> 1) & 3)) << 4;
  const int aoffc = (wm * 128 + fr) * 64 + rdc;

  // B fragment global pointers: lane l, frag ni -> row (bcol + wn*64 + ni*16 + fr),
  // bytes [fq*16, fq*16+16) of the tile's 64B k-chunk.
  const signed char* gBf0 = B + (bcol + wn * 64 + 0 * 16 + fr) * (long)K + fq * 16;
  const signed char* gBf1 = B + (bcol + wn * 64 + 1 * 16 + fr) * (long)K + fq * 16;
  const signed char* gBf2 = B + (bcol + wn * 64 + 2 * 16 + fr) * (long)K + fq * 16;
  const signed char* gBf3 = B + (bcol + wn * 64 + 3 * 16 + fr) * (long)K + fq * 16;

  v4i acc[8][4] = {};
  v4i af[8];
  v4i bfA[4], bfB[4];

  // prologue: A tile0 -> buf0; B tile0 -> bfA; drain.
  STAGE_A(0, 0);
  bfA[0] = *(const v4i*)(gBf0);
  bfA[1] = *(const v4i*)(gBf1);
  bfA[2] = *(const v4i*)(gBf2);
  bfA[3] = *(const v4i*)(gBf3);
  VM0; BAR;

  for (int t = 0; t < NT; t += 2) {
    ITER(0, bfA, bfB, t);       // consume tile t   (buf0, bfA); prefetch t+1
    ITER(1, bfB, bfA, t + 1);   // consume tile t+1 (buf1, bfB); prefetch t+2
  }

  // epilogue: out = (acc + (128 - wzp[n]) * rowsum[m]) * (iscale * wscale[n]) + bias[n]
  const float is = iscale[0];
  int rs[8][4];
#pragma unroll
  for (int mi = 0; mi < 8; ++mi)
#pragma unroll
    for (int j = 0; j < 4; ++j)
      rs[mi][j] = rowsum[(int)brow + wm * 128 + mi * 16 + fq * 4 + j];
#pragma unroll
  for (int ni = 0; ni < 4; ++ni) {
    const int col = (int)bcol + wn * 64 + ni * 16 + fr;
    const float sc = is * wscale[col];
    const int zpc = 128 - wzp[col];
    const float bi = bias[col];
#pragma unroll
    for (int mi = 0; mi < 8; ++mi) {
      const int row0 = (int)brow + wm * 128 + mi * 16 + fq * 4;
#pragma unroll
      for (int j = 0; j < 4; ++j) {
        const int v = acc[mi][ni][j] + zpc * rs[mi][j];
        C[(long)(row0 + j) * N + col] = (float)v * sc + bi;
      }
    }
  }
}

extern "C" void kernel_launch(void* const* d_in, const int* in_sizes, int n_in,
                              void* d_out, int out_size, void* d_ws, size_t ws_size,
                              hipStream_t stream) {
    const int* x_q = (const int*)d_in[0];
    const int* w_q = (const int*)d_in[1];
    const float* wscale = (const float*)d_in[2];
    const int* wzp = (const int*)d_in[3];
    const float* bias = (const float*)d_in[4];
    const float* iscale = (const float*)d_in[5];
    const int* izp = (const int*)d_in[6];

    int N = in_sizes[2];            // weight_scale has N elements
    int K = in_sizes[1] / N;        // weight is [N, K]
    int M = in_sizes[0] / K;        // x is [M, K]

    signed char* xs = (signed char*)d_ws;
    signed char* wsq = xs + (size_t)M * K;
    int* rowsum = (int*)(wsq + (size_t)N * K);

    prep_kernel<<<M + N, 256, 0, stream>>>(x_q, w_q, izp, xs, wsq, rowsum, M, K);

    int grid = (M / 256) * (N / 256);   // 512 blocks
    gemm_i8_bd<<<grid, 512, 0, stream>>>(xs, wsq, rowsum, wscale, wzp, bias, iscale,
                                         (float*)d_out, M, N, K);
}

// Round 15
// 186.656 us; speedup vs baseline: 1.4083x; 1.4083x over previous
//
#include <hip/hip_runtime.h>
#include <hip/hip_bf16.h>
#include <stdint.h>

typedef int v4i __attribute__((ext_vector_type(4)));

#define AS_GLOBAL(p) ((const __attribute__((address_space(1))) void*)(p))
#define AS_LDS(p)    ((__attribute__((address_space(3))) void*)(p))

// ---------------- merged prepass: rows [0,M) = x - izp (+rowsum); rows [M, M+N) = w - 128
__global__ __launch_bounds__(256) void prep_kernel(const int* __restrict__ x,
                                                   const int* __restrict__ w,
                                                   const int* __restrict__ izp_p,
                                                   signed char* __restrict__ xs,
                                                   signed char* __restrict__ wsq,
                                                   int* __restrict__ rowsum, int M, int K) {
    int row = blockIdx.x;
    int n4 = K >> 2;
    if (row < M) {
        int izp = izp_p[0];
        const int4* xr = (const int4*)(x + (long)row * K);
        uint32_t* xo = (uint32_t*)(xs + (long)row * K);
        int sum = 0;
        for (int i = threadIdx.x; i < n4; i += 256) {
            int4 v = xr[i];
            int a0 = v.x - izp, a1 = v.y - izp, a2 = v.z - izp, a3 = v.w - izp;
            sum += a0 + a1 + a2 + a3;
            xo[i] = (uint32_t)(a0 & 0xFF) | ((uint32_t)(a1 & 0xFF) << 8) |
                    ((uint32_t)(a2 & 0xFF) << 16) | ((uint32_t)(a3 & 0xFF) << 24);
        }
        sum += __shfl_down(sum, 32);
        sum += __shfl_down(sum, 16);
        sum += __shfl_down(sum, 8);
        sum += __shfl_down(sum, 4);
        sum += __shfl_down(sum, 2);
        sum += __shfl_down(sum, 1);
        __shared__ int red[4];
        if ((threadIdx.x & 63) == 0) red[threadIdx.x >> 6] = sum;
        __syncthreads();
        if (threadIdx.x == 0) rowsum[row] = red[0] + red[1] + red[2] + red[3];
    } else {
        int wrow = row - M;
        const int4* wr = (const int4*)(w + (long)wrow * K);
        uint32_t* wo = (uint32_t*)(wsq + (long)wrow * K);
        for (int i = threadIdx.x; i < n4; i += 256) {
            int4 v = wr[i];
            int a0 = v.x - 128, a1 = v.y - 128, a2 = v.z - 128, a3 = v.w - 128;
            wo[i] = (uint32_t)(a0 & 0xFF) | ((uint32_t)(a1 & 0xFF) << 8) |
                    ((uint32_t)(a2 & 0xFF) << 16) | ((uint32_t)(a3 & 0xFF) << 24);
        }
    }
}

// ---------------- main GEMM: 256x256 tile, BK=128 int8, 16x16x64 MFMA ----------------
// R15: R10 base with ALL lgkm pins and sched_barriers DELETED. The compiler tracks
//      the C++ ds_read->MFMA deps and emits graded per-operand lgkmcnt (m97);
//      the R2-R14 blanket {lgkm(0); sched_barrier(0)} forced a full per-wave queue
//      drain at fixed points and forbade read/MFMA interleaving (Common-mistake #5).
//      Correctness: every ds_read feeds an MFMA in its own phase, so its graded
//      wait retires it before the phase's BAR -> next phase's STAGE into that
//      region is safe. VM4 staging scheme byte-identical to R10 (validated).

#define BAR  __builtin_amdgcn_s_barrier()
#define VM4  asm volatile("s_waitcnt vmcnt(4)" ::: "memory")
#define PRIO1 __builtin_amdgcn_s_setprio(1)
#define PRIO0 __builtin_amdgcn_s_setprio(0)

#define STAGE(gbase, opofs, half, buf, tile) do {                                     \
    int t_ = (tile); if (t_ >= NT) t_ -= NT;                                          \
    const signed char* src_ = (gbase) + (long)((half) * 128) * K + (long)t_ * 128;    \
    signed char* dst_ = ldsw + (buf) * 65536 + (opofs) + (half) * 16384;              \
    __builtin_amdgcn_global_load_lds(AS_GLOBAL(src_), AS_LDS(dst_), 16, 0, 0);        \
    __builtin_amdgcn_global_load_lds(AS_GLOBAL(src_ + 64L * K), AS_LDS(dst_ + 8192), 16, 0, 0); \
  } while (0)

// afs[s][ks] holds A-frag for acc row (mb + s); storage reused across phases.
#define READ_AS(buf, s, mi) do {                                                      \
    afs[s][0] = *(const v4i*)(lds + (buf) * 65536 + aoff0 + (mi) * 2048);             \
    afs[s][1] = *(const v4i*)(lds + (buf) * 65536 + aoff1 + (mi) * 2048); } while (0)
#define READ_B(buf, ni) do {                                                          \
    bf[ni][0] = *(const v4i*)(lds + (buf) * 65536 + boff0 + (ni) * 2048);             \
    bf[ni][1] = *(const v4i*)(lds + (buf) * 65536 + boff1 + (ni) * 2048); } while (0)

#define M1(s, mi, ni, ks)                                                              \
    acc[mi][ni] = __builtin_amdgcn_mfma_i32_16x16x64_i8(afs[s][ks], bf[ni][ks], acc[mi][ni], 0, 0, 0);

// 32 MFMA for acc rows mb..mb+3 x all 4 ni: ks-outer (16 independent, then 16).
#define MFMA32(mb) do {                                                                \
    M1(0, mb + 0, 0, 0) M1(0, mb + 0, 1, 0) M1(1, mb + 1, 0, 0) M1(1, mb + 1, 1, 0)   \
    M1(2, mb + 2, 0, 0) M1(2, mb + 2, 1, 0) M1(3, mb + 3, 0, 0) M1(3, mb + 3, 1, 0)   \
    M1(0, mb + 0, 2, 0) M1(0, mb + 0, 3, 0) M1(1, mb + 1, 2, 0) M1(1, mb + 1, 3, 0)   \
    M1(2, mb + 2, 2, 0) M1(2, mb + 2, 3, 0) M1(3, mb + 3, 2, 0) M1(3, mb + 3, 3, 0)   \
    M1(0, mb + 0, 0, 1) M1(0, mb + 0, 1, 1) M1(1, mb + 1, 0, 1) M1(1, mb + 1, 1, 1)   \
    M1(2, mb + 2, 0, 1) M1(2, mb + 2, 1, 1) M1(3, mb + 3, 0, 1) M1(3, mb + 3, 1, 1)   \
    M1(0, mb + 0, 2, 1) M1(0, mb + 0, 3, 1) M1(1, mb + 1, 2, 1) M1(1, mb + 1, 3, 1)   \
    M1(2, mb + 2, 2, 1) M1(2, mb + 2, 3, 1) M1(3, mb + 3, 2, 1) M1(3, mb + 3, 3, 1)   \
  } while (0)

#define KTILE(b, tA, tB) do {                                                          \
    /* phase A: 16 reads (af0-3 both ks, bf0-3 both ks), A-stages, 32 MFMA */          \
    READ_AS(b, 0, 0); READ_AS(b, 1, 1); READ_AS(b, 2, 2); READ_AS(b, 3, 3);            \
    READ_B(b, 0); READ_B(b, 1); READ_B(b, 2); READ_B(b, 3);                            \
    STAGE(gA, 0, 0, (b) ^ 1, tA); STAGE(gA, 0, 1, (b) ^ 1, tA);                        \
    PRIO1; MFMA32(0); PRIO0;                                                           \
    BAR;                                                                               \
    /* phase B: 8 reads (af4-7 into same storage), B-stages, 32 MFMA */                \
    READ_AS(b, 0, 4); READ_AS(b, 1, 5); READ_AS(b, 2, 6); READ_AS(b, 3, 7);            \
    STAGE(gB, 32768, 0, (b), tB); STAGE(gB, 32768, 1, (b), tB);                        \
    PRIO1; MFMA32(4); PRIO0;                                                           \
    VM4; BAR;                                                                          \
  } while (0)

__global__ __launch_bounds__(512, 2) void gemm_i8_8ph(
    const signed char* __restrict__ A,   // xs [M,K]
    const signed char* __restrict__ B,   // ws [N,K]
    const int* __restrict__ rowsum, const float* __restrict__ wscale,
    const int* __restrict__ wzp, const float* __restrict__ bias,
    const float* __restrict__ iscale, float* __restrict__ C,
    int M, int N, int K) {
  __shared__ signed char lds[131072];
  const int tid = threadIdx.x;
  const int w = tid >> 6, l = tid & 63;
  const int wm = w >> 2, wn = w & 3;
  const int fr = l & 15, fq = l >> 4;

  int nwg = gridDim.x, bid = blockIdx.x;
  if ((nwg & 7) == 0) { int cpx = nwg >> 3; bid = (bid & 7) * cpx + (bid >> 3); }
  const int ntiles = N >> 8;
  const int mt = bid / ntiles, nt = bid - mt * ntiles;
  const long brow = (long)mt << 8, bcol = (long)nt << 8;

  const int NT = K >> 7;      // K-tiles of 128 bytes
  const int NI = NT >> 1;     // 2 K-tiles per iteration

  // staging lane constants (unchanged from R2)
  const int srow = w * 8 + (l >> 3);
  const int schunk = ((l & 7) ^ (l >> 3)) << 4;
  const signed char* gA = A + (brow + srow) * (long)K + schunk;
  const signed char* gB = B + (bcol + srow) * (long)K + schunk;
  signed char* ldsw = lds + w * 1024;   // wave-uniform LDS dest component

  // fragment read offsets (swizzled chunk = (ks*4+fq) ^ (fr&7))
  const int axor = fr & 7;
  const int aoff0 = (wm * 128 + fr) * 128 + ((fq ^ axor) << 4);
  const int aoff1 = (wm * 128 + fr) * 128 + (((4 + fq) ^ axor) << 4);
  const int boff0 = 32768 + (wn * 64 + fr) * 128 + ((fq ^ axor) << 4);
  const int boff1 = 32768 + (wn * 64 + fr) * 128 + (((4 + fq) ^ axor) << 4);

  v4i acc[8][4] = {};
  v4i afs[4][2], bf[4][2];   // 16 live v4i fragments max

  // prologue: tile0 -> buf0 (B,A), tile1 B -> buf1; wait first 8, keep 4 in flight
  STAGE(gB, 32768, 0, 0, 0); STAGE(gB, 32768, 1, 0, 0);
  STAGE(gA, 0, 0, 0, 0);     STAGE(gA, 0, 1, 0, 0);
  STAGE(gB, 32768, 0, 1, 1); STAGE(gB, 32768, 1, 1, 1);
  VM4; BAR;

  for (int i = 0; i < NI; ++i) {
    const int t1 = 2 * i + 1, t2 = 2 * i + 2, t3 = 2 * i + 3;
    KTILE(0, t1, t2);   // K-tile 2i   from buf0
    KTILE(1, t2, t3);   // K-tile 2i+1 from buf1
  }

  // epilogue: out = (acc + (128 - wzp[n]) * rowsum[m]) * (iscale * wscale[n]) + bias[n]
  const float is = iscale[0];
  int rs[8][4];
#pragma unroll
  for (int mi = 0; mi < 8; ++mi)
#pragma unroll
    for (int j = 0; j < 4; ++j)
      rs[mi][j] = rowsum[(int)brow + wm * 128 + mi * 16 + fq * 4 + j];
#pragma unroll
  for (int ni = 0; ni < 4; ++ni) {
    const int col = (int)bcol + wn * 64 + ni * 16 + fr;
    const float sc = is * wscale[col];
    const int zpc = 128 - wzp[col];
    const float bi = bias[col];
#pragma unroll
    for (int mi = 0; mi < 8; ++mi) {
      const int row0 = (int)brow + wm * 128 + mi * 16 + fq * 4;
#pragma unroll
      for (int j = 0; j < 4; ++j) {
        const int v = acc[mi][ni][j] + zpc * rs[mi][j];
        C[(long)(row0 + j) * N + col] = (float)v * sc + bi;
      }
    }
  }
}

extern "C" void kernel_launch(void* const* d_in, const int* in_sizes, int n_in,
                              void* d_out, int out_size, void* d_ws, size_t ws_size,
                              hipStream_t stream) {
    const int* x_q = (const int*)d_in[0];
    const int* w_q = (const int*)d_in[1];
    const float* wscale = (const float*)d_in[2];
    const int* wzp = (const int*)d_in[3];
    const float* bias = (const float*)d_in[4];
    const float* iscale = (const float*)d_in[5];
    const int* izp = (const int*)d_in[6];

    int N = in_sizes[2];            // weight_scale has N elements
    int K = in_sizes[1] / N;        // weight is [N, K]
    int M = in_sizes[0] / K;        // x is [M, K]

    signed char* xs = (signed char*)d_ws;
    signed char* wsq = xs + (size_t)M * K;
    int* rowsum = (int*)(wsq + (size_t)N * K);

    prep_kernel<<<M + N, 256, 0, stream>>>(x_q, w_q, izp, xs, wsq, rowsum, M, K);

    int grid = (M / 256) * (N / 256);
    gemm_i8_8ph<<<grid, 512, 0, stream>>>(xs, wsq, rowsum, wscale, wzp, bias, iscale,
                                          (float*)d_out, M, N, K);
}